// Round 10
// baseline (229.825 us; speedup 1.0000x reference)
//
#include <hip/hip_runtime.h>
#include <math.h>

#define CDIM 1024
#define TC   3072
#define NIN  2048   // input rows per batch (class token handled separately)

// workspace float offsets (every slot written before read; ctrs zeroed by k_q0)
#define F_Q0P 0           // 16*1024 q0 i-chunk partials
#define F_WS  16384       // 4*1024  [h][c]
#define F_PS  20480       // 1024*4  per-block exp-sums
#define F_PY  24576       // 1024*4096 per-block y partials, natural [h][c]
#define F_OCP 4218880     // 8(q)*8(b)*1024 oc partials
#define F_CTR 4284416     // 2 uint barrier counters

// ---- dispatch 1: q0 partials + zero d_out + zero barrier counters ----
__global__ __launch_bounds__(256) void k_q0(const float* __restrict__ t,
                                            const float* __restrict__ W,
                                            float* __restrict__ wsb,
                                            float* __restrict__ out) {
    int blk = blockIdx.x, tid = threadIdx.x;
    if (blk == 0 && tid < 2) ((unsigned int*)(wsb + F_CTR))[tid] = 0u;
    if (blk < 32) out[blk * 256 + tid] = 0.f;
    int ic = blk >> 2, jc = blk & 3;             // 16 i-chunks of 64, 4 j-chunks of 256
    int j = jc * 256 + tid;
    int i0 = ic * 64;
    float acc = 0.f;
    for (int i = 0; i < 64; ++i)
        acc += t[i0 + i] * W[(size_t)(i0 + i) * TC + j];
    wsb[F_Q0P + ic * CDIM + j] = acc;
}

// ---- dispatch 2: Ws[h][c] = Wk[c, h-slice] . (q0 + bq) ----
__global__ __launch_bounds__(256) void k_ws(const float* __restrict__ W,
                                            const float* __restrict__ bqkv,
                                            float* __restrict__ wsb) {
    int wave = threadIdx.x >> 6, lane = threadIdx.x & 63;
    int c = blockIdx.x, h = wave;
    int d0 = h * 256 + lane * 4;
    float4 wv = *(const float4*)&W[(size_t)c * TC + CDIM + d0];
    float4 q = *(const float4*)&bqkv[d0];
#pragma unroll
    for (int ic = 0; ic < 16; ++ic) {
        float4 p = *(const float4*)&wsb[F_Q0P + ic * CDIM + d0];
        q.x += p.x; q.y += p.y; q.z += p.z; q.w += p.w;
    }
    float acc = wv.x * q.x + wv.y * q.y + wv.z * q.z + wv.w * q.w;
    for (int off = 32; off > 0; off >>= 1) acc += __shfl_down(acc, off);
    if (lane == 0) wsb[F_WS + h * CDIM + c] = acc;
}

// ---- dispatch 3: pass1 (1024 blocks, R6 geometry) -> ctr0 -> comb+ocy (32) ->
//      ctr1 -> out (64). Only blocks 0..95 ever wait; all feeders are
//      non-waiting -> deadlock-free regardless of scheduling/co-residency.
__global__ __launch_bounds__(256) void k_mega(
    const float* __restrict__ x, const float* __restrict__ t,
    const float* __restrict__ Wqkv, const float* __restrict__ bqkv,
    const float* __restrict__ Wv, const float* __restrict__ bv,
    float* __restrict__ wsb, float* __restrict__ out)
{
    __shared__ float ybuf[4 * CDIM];
    __shared__ float aux[80];
    int tid = threadIdx.x, lane = tid & 63, wave = tid >> 6;
    int blk = blockIdx.x;
    unsigned int* ctr = (unsigned int*)(wsb + F_CTR);

    // ---------- phase PASS1: X scan (R6-proven: 1024 blocks, wave owns 4 rows) ----------
    {
        float4 wsr[4][4];
#pragma unroll
        for (int k = 0; k < 4; ++k)
#pragma unroll
            for (int h = 0; h < 4; ++h)
                wsr[k][h] = *(const float4*)&wsb[F_WS + h * CDIM + k * 256 + lane * 4];
        float s[4] = {0.f, 0.f, 0.f, 0.f};
        float4 y[4][4];
#pragma unroll
        for (int h = 0; h < 4; ++h)
#pragma unroll
            for (int k = 0; k < 4; ++k) y[h][k] = make_float4(0.f, 0.f, 0.f, 0.f);
        int b = blk >> 7, ch = blk & 127;
        const float* base = x + ((size_t)b * NIN + ch * 16 + wave * 4) * CDIM;
#pragma unroll 2
        for (int i = 0; i < 4; ++i) {
            const float* row = base + (size_t)i * CDIM;
            float4 xv[4];
#pragma unroll
            for (int k = 0; k < 4; ++k) xv[k] = *(const float4*)&row[k * 256 + lane * 4];
            float e[4];
#pragma unroll
            for (int h = 0; h < 4; ++h) {
                float a = 0.f;
#pragma unroll
                for (int k = 0; k < 4; ++k)
                    a += xv[k].x * wsr[k][h].x + xv[k].y * wsr[k][h].y +
                         xv[k].z * wsr[k][h].z + xv[k].w * wsr[k][h].w;
                for (int off = 1; off < 64; off <<= 1) a += __shfl_xor(a, off);
                e[h] = __expf(a * 0.0625f);   // Dh=256 -> 1/16; +ck cancels in softmax
            }
#pragma unroll
            for (int h = 0; h < 4; ++h) {
                float f = e[h];
                s[h] += f;
#pragma unroll
                for (int k = 0; k < 4; ++k) {
                    y[h][k].x += f * xv[k].x; y[h][k].y += f * xv[k].y;
                    y[h][k].z += f * xv[k].z; y[h][k].w += f * xv[k].w;
                }
            }
        }
        // sequential 4-wave merge through LDS (R6-proven)
        if (lane == 0)
#pragma unroll
            for (int h = 0; h < 4; ++h) aux[wave * 4 + h] = s[h];
        for (int idx = tid; idx < 4 * CDIM; idx += 256) ybuf[idx] = 0.f;
        __syncthreads();
        for (int w = 0; w < 4; ++w) {
            if (wave == w) {
#pragma unroll
                for (int h = 0; h < 4; ++h)
#pragma unroll
                    for (int k = 0; k < 4; ++k) {
                        float4* dst = (float4*)&ybuf[h * CDIM + k * 256 + lane * 4];
                        float4 v = *dst;
                        v.x += y[h][k].x; v.y += y[h][k].y;
                        v.z += y[h][k].z; v.w += y[h][k].w;
                        *dst = v;
                    }
            }
            __syncthreads();
        }
        if (tid < 4)
            wsb[F_PS + blk * 4 + tid] = aux[tid] + aux[4 + tid] + aux[8 + tid] + aux[12 + tid];
        for (int idx = tid; idx < 4 * CDIM; idx += 256)
            wsb[F_PY + (size_t)blk * 4096 + idx] = ybuf[idx];
    }
    // arrive at ctr0 (producers never wait)
    __syncthreads();
    if (tid == 0) { __threadfence(); atomicAdd(&ctr[0], 1u); }
    if (blk >= 96) return;

    // ---------- phase COMBOCY (blocks 0..31): ybar slice + V-projection partials ----------
    if (blk < 32) {
        if (tid == 0) {
            while (__hip_atomic_load(&ctr[0], __ATOMIC_RELAXED, __HIP_MEMORY_SCOPE_AGENT) < 1024u)
                __builtin_amdgcn_s_sleep(2);
            __threadfence();
        }
        __syncthreads();
        int h = blk >> 3, q = blk & 7;
        // sc0 = (t . Ws_h)/16
        {
            float4 tv = *(const float4*)&t[tid * 4];
            float4 wsv = *(const float4*)&wsb[F_WS + h * CDIM + tid * 4];
            float p = tv.x * wsv.x + tv.y * wsv.y + tv.z * wsv.z + tv.w * wsv.w;
            for (int off = 1; off < 64; off <<= 1) p += __shfl_xor(p, off);
            if (lane == 0) aux[64 + wave] = p;
        }
        __syncthreads();
        float e0 = __expf((aux[64] + aux[65] + aux[66] + aux[67]) * 0.0625f);
        // S[b] = e0 + sum of 128 PS partials per (b,h)
        if (tid < 64) {
            int b = tid >> 3, g = tid & 7;
            float sv = 0.f;
#pragma unroll
            for (int i = 0; i < 16; ++i)
                sv += wsb[F_PS + (size_t)(b * 128 + g * 16 + i) * 4 + h];
            aux[tid] = sv;
        }
        __syncthreads();
        if (tid < 8) {
            float S = e0;
#pragma unroll
            for (int k = 0; k < 8; ++k) S += aux[tid * 8 + k];
            aux[64 + tid] = 1.f / S;
        }
        __syncthreads();
        // ybar[b][h][q*128..+128] -> first 1024 floats of ybuf
        {
            int b = tid >> 5, cc0 = (tid & 31) * 4;
            const float* tp = &t[q * 128 + cc0];
            float4 acc = make_float4(e0 * tp[0], e0 * tp[1], e0 * tp[2], e0 * tp[3]);
#pragma unroll 4
            for (int m = 0; m < 128; ++m) {
                float4 p = *(const float4*)&wsb[F_PY + (size_t)(b * 128 + m) * 4096 + h * 1024 + q * 128 + cc0];
                acc.x += p.x; acc.y += p.y; acc.z += p.z; acc.w += p.w;
            }
            float si = aux[64 + b];
            ybuf[b * 128 + cc0]     = acc.x * si;
            ybuf[b * 128 + cc0 + 1] = acc.y * si;
            ybuf[b * 128 + cc0 + 2] = acc.z * si;
            ybuf[b * 128 + cc0 + 3] = acc.w * si;
        }
        __syncthreads();
        // ocp[q][b][cp] for cp in h's 256-range
        {
            int cp = h * 256 + tid;
            float acc8[8] = {0.f, 0.f, 0.f, 0.f, 0.f, 0.f, 0.f, 0.f};
            for (int cc = 0; cc < 128; ++cc) {
                float w = Wqkv[(size_t)(q * 128 + cc) * TC + 2 * CDIM + cp];
#pragma unroll
                for (int b = 0; b < 8; ++b) acc8[b] += ybuf[b * 128 + cc] * w;
            }
            if (q == 0) {
                float bias = bqkv[2 * CDIM + cp];
#pragma unroll
                for (int b = 0; b < 8; ++b) acc8[b] += bias;
            }
#pragma unroll
            for (int b = 0; b < 8; ++b)
                wsb[F_OCP + (size_t)(q * 8 + b) * CDIM + cp] = acc8[b];
        }
        __syncthreads();
        if (tid == 0) { __threadfence(); atomicAdd(&ctr[1], 1u); }
        return;
    }

    // ---------- phase OUT (blocks 32..95): out[b][j] = oc[b].Wv[:,j] + bv ----------
    {
        if (tid == 0) {
            while (__hip_atomic_load(&ctr[1], __ATOMIC_RELAXED, __HIP_MEMORY_SCOPE_AGENT) < 32u)
                __builtin_amdgcn_s_sleep(2);
            __threadfence();
        }
        __syncthreads();
        int ob = blk - 32, jp = ob >> 3, cq = ob & 7;
        // stage oc[b][cq-slice] (sum 8 q-partials): 1024 slots, 4 per thread
#pragma unroll
        for (int r = 0; r < 4; ++r) {
            int idx = r * 256 + tid;
            int bb = idx >> 7, cc = idx & 127;
            float sum = 0.f;
#pragma unroll
            for (int q = 0; q < 8; ++q)
                sum += wsb[F_OCP + (size_t)(q * 8 + bb) * CDIM + cq * 128 + cc];
            ybuf[idx] = sum;
        }
        __syncthreads();
        if (tid < 128) {
            int j = jp * 128 + tid;
            float acc8[8] = {0.f, 0.f, 0.f, 0.f, 0.f, 0.f, 0.f, 0.f};
            for (int c = 0; c < 128; ++c) {
                float w = Wv[(size_t)(cq * 128 + c) * CDIM + j];
#pragma unroll
                for (int bb = 0; bb < 8; ++bb) acc8[bb] += ybuf[bb * 128 + c] * w;
            }
            if (cq == 0) {
                float bias = bv[j];
#pragma unroll
                for (int bb = 0; bb < 8; ++bb) acc8[bb] += bias;
            }
#pragma unroll
            for (int bb = 0; bb < 8; ++bb) atomicAdd(&out[bb * CDIM + j], acc8[bb]);
        }
    }
}

extern "C" void kernel_launch(void* const* d_in, const int* in_sizes, int n_in,
                              void* d_out, int out_size, void* d_ws, size_t ws_size,
                              hipStream_t stream) {
    const float* x    = (const float*)d_in[0];   // [8,2048,1024]
    const float* t    = (const float*)d_in[1];   // [1,1,1024]
    const float* Wqkv = (const float*)d_in[2];   // [1024,3072]
    const float* bqkv = (const float*)d_in[3];   // [3072]
    const float* Wv   = (const float*)d_in[4];   // [1024,1024]
    const float* bv   = (const float*)d_in[5];   // [1024]
    float* wsb = (float*)d_ws;
    float* out = (float*)d_out;                  // [8,1024] fp32

    k_q0  <<<64,   256, 0, stream>>>(t, Wqkv, wsb, out);
    k_ws  <<<1024, 256, 0, stream>>>(Wqkv, bqkv, wsb);
    k_mega<<<1024, 256, 0, stream>>>(x, t, Wqkv, bqkv, Wv, bv, wsb, out);
}

// Round 11
// 170.146 us; speedup vs baseline: 1.3507x; 1.3507x over previous
//
#include <hip/hip_runtime.h>
#include <math.h>

#define CDIM 1024
#define TC   3072
#define NIN  2048   // input rows per batch (class token handled separately)

// workspace float offsets (every slot written before read; no zero-init needed)
#define OFF_Q0P 0           // 16*1024 q0 i-chunk partials
#define OFF_WS  16384       // 4*1024  [h][c]
#define OFF_PS  20480       // 512*4   per-block exp-sums
#define OFF_PY  24576       // 512*4096 partial weighted x-sums
#define OFF_YB  2121728     // 8*4*1024 attention-averaged rows
#define OFF_OCP 2154496     // 8(q)*8(b)*1024 oc partials

// ---- q0 partials: q0p[ic][j] = sum_{i in chunk ic} t[i] * Wqkv[i, j] ----
__global__ void k_q0(const float* __restrict__ t, const float* __restrict__ W,
                     float* __restrict__ wsb) {
    int ic = blockIdx.x >> 3, jc = blockIdx.x & 7;   // 16 i-chunks x 8 j-chunks
    int j = jc * 128 + threadIdx.x;
    int i0 = ic * 64;
    float acc = 0.f;
    for (int i = 0; i < 64; ++i)
        acc += t[i0 + i] * W[(size_t)(i0 + i) * TC + j];
    wsb[OFF_Q0P + ic * CDIM + j] = acc;
}

// ---- Ws[h][c] = sum_d Wk[c, h*256+d] * (q0[d^] + bq[d^]) ----
__global__ void k_ws(const float* __restrict__ W, const float* __restrict__ bqkv,
                     float* __restrict__ wsb) {
    int wave = threadIdx.x >> 6, lane = threadIdx.x & 63;
    int c = blockIdx.x, h = wave;
    int d0 = h * 256 + lane * 4;
    float4 wv = *(const float4*)&W[(size_t)c * TC + CDIM + d0];
    float4 q = *(const float4*)&bqkv[d0];
#pragma unroll
    for (int ic = 0; ic < 16; ++ic) {
        float4 p = *(const float4*)&wsb[OFF_Q0P + ic * CDIM + d0];
        q.x += p.x; q.y += p.y; q.z += p.z; q.w += p.w;
    }
    float acc = wv.x * q.x + wv.y * q.y + wv.z * q.z + wv.w * q.w;
    for (int off = 32; off > 0; off >>= 1) acc += __shfl_down(acc, off);
    if (lane == 0) wsb[OFF_WS + h * CDIM + c] = acc;
}

// ---- single pass over X: exp(score) + weighted row-sum (no max-shift:
//      scores O(+-5), verified absmax 2.2e-8) ----
// 512 blocks x 256 thr; block = (b, 32-row chunk); wave owns 8 rows (R2-proven).
__global__ __launch_bounds__(256) void k_pass1(const float* __restrict__ x,
                                               float* __restrict__ wsb) {
    int tid = threadIdx.x, lane = tid & 63, wave = tid >> 6;
    int b = blockIdx.x >> 6, blkc = blockIdx.x & 63;

    float4 wsr[4][4];
#pragma unroll
    for (int k = 0; k < 4; ++k)
#pragma unroll
        for (int h = 0; h < 4; ++h)
            wsr[k][h] = *(const float4*)&wsb[OFF_WS + h * CDIM + k * 256 + lane * 4];

    float s[4] = {0.f, 0.f, 0.f, 0.f};
    float4 y[4][4];
#pragma unroll
    for (int h = 0; h < 4; ++h)
#pragma unroll
        for (int k = 0; k < 4; ++k) y[h][k] = make_float4(0.f, 0.f, 0.f, 0.f);

    const float* base = x + ((size_t)b * NIN + blkc * 32 + wave * 8) * CDIM;
#pragma unroll 4
    for (int i = 0; i < 8; ++i) {
        const float* row = base + (size_t)i * CDIM;
        float4 xv[4];
#pragma unroll
        for (int k = 0; k < 4; ++k) xv[k] = *(const float4*)&row[k * 256 + lane * 4];
        float e[4];
#pragma unroll
        for (int h = 0; h < 4; ++h) {
            float a = 0.f;
#pragma unroll
            for (int k = 0; k < 4; ++k)
                a += xv[k].x * wsr[k][h].x + xv[k].y * wsr[k][h].y +
                     xv[k].z * wsr[k][h].z + xv[k].w * wsr[k][h].w;
            for (int off = 1; off < 64; off <<= 1) a += __shfl_xor(a, off);
            e[h] = __expf(a * 0.0625f);   // Dh=256 -> 1/16; +ck cancels in softmax
        }
#pragma unroll
        for (int h = 0; h < 4; ++h) {
            float f = e[h];
            s[h] += f;
#pragma unroll
            for (int k = 0; k < 4; ++k) {
                y[h][k].x += f * xv[k].x; y[h][k].y += f * xv[k].y;
                y[h][k].z += f * xv[k].z; y[h][k].w += f * xv[k].w;
            }
        }
    }

    // block merge of 4 wave states via LDS (plain sums)
    __shared__ float ss[4][4];
    __shared__ float ybuf[4][CDIM];
    if (lane == 0)
#pragma unroll
        for (int h = 0; h < 4; ++h) ss[wave][h] = s[h];
    for (int idx = tid; idx < 4 * CDIM; idx += 256) ((float*)ybuf)[idx] = 0.f;
    __syncthreads();
    for (int w = 0; w < 4; ++w) {
        if (wave == w) {
#pragma unroll
            for (int h = 0; h < 4; ++h)
#pragma unroll
                for (int k = 0; k < 4; ++k) {
                    float4* dst = (float4*)&ybuf[h][k * 256 + lane * 4];
                    float4 v = *dst;
                    v.x += y[h][k].x; v.y += y[h][k].y;
                    v.z += y[h][k].z; v.w += y[h][k].w;
                    *dst = v;
                }
        }
        __syncthreads();
    }
    int p = blockIdx.x;
    if (tid < 4)
        wsb[OFF_PS + p * 4 + tid] = ss[0][tid] + ss[1][tid] + ss[2][tid] + ss[3][tid];
    for (int idx = tid; idx < 4 * CDIM; idx += 256)
        wsb[OFF_PY + (size_t)p * 4096 + idx] = ((float*)ybuf)[idx];
}

// ---- combine 64 chunk-partials per (b,h) + class-token term -> ybar[b][h][c] ----
__global__ void k_comb(const float* __restrict__ t, float* __restrict__ wsb) {
    int tid = threadIdx.x, lane = tid & 63, wv = tid >> 6;
    int blk = blockIdx.x;
    int b = blk >> 4, h = (blk >> 2) & 3, cq = blk & 3;
    __shared__ float red[4], redS[4];

    // sc0 = (t . Ws_h) / 16
    int c0 = tid * 4;
    float4 tv = *(const float4*)&t[c0];
    float4 wsv = *(const float4*)&wsb[OFF_WS + h * CDIM + c0];
    float p = tv.x * wsv.x + tv.y * wsv.y + tv.z * wsv.z + tv.w * wsv.w;
    for (int off = 1; off < 64; off <<= 1) p += __shfl_xor(p, off);
    if (lane == 0) red[wv] = p;

    float sv = (tid < 64) ? wsb[OFF_PS + (size_t)(b * 64 + tid) * 4 + h] : 0.f;
    for (int off = 1; off < 64; off <<= 1) sv += __shfl_xor(sv, off);
    if (lane == 0) redS[wv] = sv;
    __syncthreads();
    float sc0 = (red[0] + red[1] + red[2] + red[3]) * 0.0625f;
    float e0 = __expf(sc0);
    float S = redS[0] + redS[1] + redS[2] + redS[3] + e0;

    int c = cq * 256 + tid;
    float acc = e0 * t[c];
#pragma unroll 4
    for (int j = 0; j < 64; ++j)
        acc += wsb[OFF_PY + (size_t)(b * 64 + j) * 4096 + h * CDIM + c];
    wsb[OFF_YB + (size_t)(b * 4 + h) * CDIM + c] = acc / S;
}

// ---- ocp[q][b][c'] partials of ybar[b][h(c')] . Wqkv[:, 2C+c'] ; also zero out ----
__global__ void k_ocy(const float* __restrict__ W, const float* __restrict__ bqkv,
                      float* __restrict__ wsb, float* __restrict__ out) {
    // fold d_out zeroing in here (runs before k_out in stream order)
    out[blockIdx.x * 128 + threadIdx.x] = 0.f;

    int p = blockIdx.x >> 3, q = blockIdx.x & 7;
    int h = p >> 1;
    __shared__ float sL[1024];
    for (int bb = 0; bb < 8; ++bb)
        sL[bb * 128 + threadIdx.x] = wsb[OFF_YB + (size_t)(bb * 4 + h) * CDIM + q * 128 + threadIdx.x];
    __syncthreads();
    int cp = p * 128 + threadIdx.x;
    float acc[8] = {0.f, 0.f, 0.f, 0.f, 0.f, 0.f, 0.f, 0.f};
    for (int c = 0; c < 128; ++c) {
        float wv = W[(size_t)(q * 128 + c) * TC + 2 * CDIM + cp];
#pragma unroll
        for (int bb = 0; bb < 8; ++bb) acc[bb] += sL[bb * 128 + c] * wv;
    }
    if (q == 0) {
        float bias = bqkv[2 * CDIM + cp];
#pragma unroll
        for (int bb = 0; bb < 8; ++bb) acc[bb] += bias;
    }
#pragma unroll
    for (int bb = 0; bb < 8; ++bb)
        wsb[OFF_OCP + (size_t)(q * 8 + bb) * CDIM + cp] = acc[bb];
}

// ---- out[b][j] = oc[b] . Wv[:, j] + bv  (sum ocp q-partials at load) ----
__global__ void k_out(const float* __restrict__ Wv, const float* __restrict__ bv,
                      const float* __restrict__ wsb, float* __restrict__ out) {
    int jp = blockIdx.x >> 3, cq = blockIdx.x & 7;
    __shared__ float ocL[1024];
    for (int bb = 0; bb < 8; ++bb) {
        float sum = 0.f;
#pragma unroll
        for (int q = 0; q < 8; ++q)
            sum += wsb[OFF_OCP + (size_t)(q * 8 + bb) * CDIM + cq * 128 + threadIdx.x];
        ocL[bb * 128 + threadIdx.x] = sum;
    }
    __syncthreads();
    int j = jp * 128 + threadIdx.x;
    float acc[8] = {0.f, 0.f, 0.f, 0.f, 0.f, 0.f, 0.f, 0.f};
    for (int c = 0; c < 128; ++c) {
        float wv = Wv[(size_t)(cq * 128 + c) * CDIM + j];
#pragma unroll
        for (int bb = 0; bb < 8; ++bb) acc[bb] += ocL[bb * 128 + c] * wv;
    }
    if (cq == 0) {
        float bias = bv[j];
#pragma unroll
        for (int bb = 0; bb < 8; ++bb) acc[bb] += bias;
    }
#pragma unroll
    for (int bb = 0; bb < 8; ++bb) atomicAdd(&out[bb * CDIM + j], acc[bb]);
}

extern "C" void kernel_launch(void* const* d_in, const int* in_sizes, int n_in,
                              void* d_out, int out_size, void* d_ws, size_t ws_size,
                              hipStream_t stream) {
    const float* x    = (const float*)d_in[0];   // [8,2048,1024]
    const float* t    = (const float*)d_in[1];   // [1,1,1024]
    const float* Wqkv = (const float*)d_in[2];   // [1024,3072]
    const float* bqkv = (const float*)d_in[3];   // [3072]
    const float* Wv   = (const float*)d_in[4];   // [1024,1024]
    const float* bv   = (const float*)d_in[5];   // [1024]
    float* wsb = (float*)d_ws;
    float* out = (float*)d_out;                  // [8,1024] fp32

    k_q0   <<<128,  128, 0, stream>>>(t, Wqkv, wsb);
    k_ws   <<<1024, 256, 0, stream>>>(Wqkv, bqkv, wsb);
    k_pass1<<<512,  256, 0, stream>>>(x, wsb);
    k_comb <<<128,  256, 0, stream>>>(t, wsb);
    k_ocy  <<<64,   128, 0, stream>>>(Wqkv, bqkv, wsb, out);
    k_out  <<<64,   128, 0, stream>>>(Wv, bv, wsb, out);
}